// Round 4
// baseline (546.102 us; speedup 1.0000x reference)
//
#include <hip/hip_runtime.h>
#include <math.h>

// ---------------------------------------------------------------------------
// Fused MoE top-2 router, MI355X (gfx950) — round 4.
// R3 diagnosis: 8 tok/wave, no k-split -> 1024 waves total = 1 wave/SIMD ->
// zero latency hiding (VALUBusy 18%). Fix: split K 4-ways -> 1024 blocks =
// 4 blocks/CU = 4 waves/SIMD. Deterministic slab partials in ws (no atomics
// on the top-k path), pass2 reduces + softmax/top-2/losses.
// Lane tile 8 tok x 8 exp (acc=64 regs, ~120 live): W float4 feeds 32 FMAs
// -> 0.5 B/FMA LDS demand (50% of pipe). lane = eg*8+ks so every 8-lane
// octet reads contiguous 128B from LDS (conflict-free) and x loads coalesce.
// ---------------------------------------------------------------------------

#define NT 8192
#define ND 4096
#define NE 64
#define TB 32
#define BK 64
#define SLAB_OFF 512   // floats; ws[0..129] = scalars

__device__ __forceinline__ void gload16(const float* g, float* l) {
    __builtin_amdgcn_global_load_lds(
        (const __attribute__((address_space(1))) void*)g,
        (__attribute__((address_space(3))) void*)l, 16, 0, 0);
}

__global__ __launch_bounds__(256, 4)
void pass1(const float* __restrict__ x, const float* __restrict__ W,
           float* __restrict__ ws, int kq_bits, int nchunk)
{
    __shared__ float wbuf[2][NE * BK];   // 2 x 16 KiB

    const int tid  = threadIdx.x;
    const int wave = tid >> 6;
    const int lane = tid & 63;
    const int eg   = lane >> 3;          // expert octet 0..7
    const int ks   = lane & 7;           // k slice 0..7 (x 4 floats)

    const int bq   = blockIdx.x >> 8;    // k-quarter index
    const int tb   = blockIdx.x & 255;
    const int tok0 = tb * TB + wave * 8; // this wave's 8 tokens
    const int k0   = bq * (ND >> kq_bits);

    float acc[8][8];
    #pragma unroll
    for (int t = 0; t < 8; t++)
        #pragma unroll
        for (int e = 0; e < 8; e++) acc[t][e] = 0.f;

    // stage chunk 0 into buffer 0 (1024 float4 slots / 256 threads)
    #pragma unroll
    for (int r = 0; r < 4; r++) {
        int s = r * 256 + tid;
        int e = s >> 4, q = s & 15;
        gload16(W + (size_t)e * ND + k0 + q * 4, &wbuf[0][s << 2]);
    }
    __syncthreads();

    const float* xrow = x + (size_t)tok0 * ND + k0 + ks * 4;

    #pragma unroll 1
    for (int c = 0; c < nchunk; ++c) {
        const int b = c & 1;
        if (c + 1 < nchunk) {
            const int koff = k0 + (c + 1) * BK;
            #pragma unroll
            for (int r = 0; r < 4; r++) {
                int s = r * 256 + tid;
                int e = s >> 4, q = s & 15;
                gload16(W + (size_t)e * ND + koff + q * 4, &wbuf[b ^ 1][s << 2]);
            }
        }
        #pragma unroll
        for (int kk = 0; kk < 2; kk++) {
            float4 xv[8];
            #pragma unroll
            for (int t = 0; t < 8; t++)
                xv[t] = *reinterpret_cast<const float4*>(
                    xrow + (size_t)t * ND + c * BK + kk * 32);
            const float* wb = &wbuf[b][(eg * 8) * BK + kk * 32 + ks * 4];
            #pragma unroll
            for (int e = 0; e < 8; e++) {
                const float4 wv = *reinterpret_cast<const float4*>(wb + e * BK);
                #pragma unroll
                for (int t = 0; t < 8; t++) {
                    float a = acc[t][e];
                    a = fmaf(xv[t].x, wv.x, a);
                    a = fmaf(xv[t].y, wv.y, a);
                    a = fmaf(xv[t].z, wv.z, a);
                    a = fmaf(xv[t].w, wv.w, a);
                    acc[t][e] = a;
                }
            }
        }
        __syncthreads();
    }

    // reduce over ks (lane bits 0..2) — butterfly within each octet
    #pragma unroll
    for (int t = 0; t < 8; t++)
        #pragma unroll
        for (int e = 0; e < 8; e++) {
            float v = acc[t][e];
            v += __shfl_xor(v, 1);
            v += __shfl_xor(v, 2);
            v += __shfl_xor(v, 4);
            acc[t][e] = v;
        }

    // lane with ks==t writes token t's 8 experts (8 egs x 32B = 256B/token)
    float* slab = ws + SLAB_OFF + ((size_t)bq * NT + tok0) * NE;
    #pragma unroll
    for (int t = 0; t < 8; t++) {
        if (ks == t) {
            *reinterpret_cast<float4*>(slab + (size_t)t * NE + eg * 8) =
                make_float4(acc[t][0], acc[t][1], acc[t][2], acc[t][3]);
            *reinterpret_cast<float4*>(slab + (size_t)t * NE + eg * 8 + 4) =
                make_float4(acc[t][4], acc[t][5], acc[t][6], acc[t][7]);
        }
    }
}

__global__ __launch_bounds__(256)
void pass2(float* __restrict__ ws, float* __restrict__ out, int kq)
{
    __shared__ float imp_s[NE];
    __shared__ float load_s[NE];
    const int tid  = threadIdx.x;
    const int lane = tid & 63;
    if (tid < NE) { imp_s[tid] = 0.f; load_s[tid] = 0.f; }
    __syncthreads();

    const int tok = blockIdx.x * 256 + tid;
    float lgv[NE];
    {
        const float* p0 = ws + SLAB_OFF + (size_t)tok * NE;
        #pragma unroll
        for (int e4 = 0; e4 < 16; e4++) {
            float4 v = *reinterpret_cast<const float4*>(p0 + e4 * 4);
            lgv[e4*4+0] = v.x; lgv[e4*4+1] = v.y;
            lgv[e4*4+2] = v.z; lgv[e4*4+3] = v.w;
        }
        for (int q = 1; q < kq; q++) {
            const float* pq = ws + SLAB_OFF + ((size_t)q * NT + tok) * NE;
            #pragma unroll
            for (int e4 = 0; e4 < 16; e4++) {
                float4 v = *reinterpret_cast<const float4*>(pq + e4 * 4);
                lgv[e4*4+0] += v.x; lgv[e4*4+1] += v.y;
                lgv[e4*4+2] += v.z; lgv[e4*4+3] += v.w;
            }
        }
    }

    float m = -3.0e38f;
    #pragma unroll
    for (int e = 0; e < NE; e++) m = fmaxf(m, lgv[e]);
    float se = 0.f, ssum = 0.f;
    #pragma unroll
    for (int e = 0; e < NE; e++) { ssum += lgv[e]; se += __expf(lgv[e] - m); }
    const float lse = m + __logf(se);
    const float inv = 1.f / se;

    // convert logits -> probs in place (exp is monotonic: top-2 order same)
    #pragma unroll
    for (int e = 0; e < NE; e++) lgv[e] = __expf(lgv[e] - m) * inv;

    // top-2 on probs (strict > keeps lower index on ties, matching lax.top_k)
    float v1 = -3.0e38f, v2 = -3.0e38f;
    int   i1 = 0, i2 = 0;
    #pragma unroll
    for (int e = 0; e < NE; e++) {
        const float v = lgv[e];
        if (v > v1)      { v2 = v1; i2 = i1; v1 = v; i1 = e; }
        else if (v > v2) { v2 = v;  i2 = e; }
    }
    const float dn = fmaxf(v1 + v2, 1e-9f);

    out[2 * tok]              = (float)i1;
    out[2 * tok + 1]          = (float)i2;
    out[2 * NT + 2 * tok]     = v1 / dn;
    out[2 * NT + 2 * tok + 1] = v2 / dn;
    atomicAdd(&load_s[i1], 1.0f);

    // z-loss + logits-sum: wave reduce, one atomic per wave
    float zv = lse * lse, sv = ssum;
    #pragma unroll
    for (int mk = 1; mk < 64; mk <<= 1) {
        zv += __shfl_xor(zv, mk);
        sv += __shfl_xor(sv, mk);
    }
    if (lane == 0) { atomicAdd(&ws[128], zv); atomicAdd(&ws[129], sv); }

    // importance: per-expert wave reduce; lane e keeps expert e's sum
    float impacc = 0.f;
    #pragma unroll
    for (int e = 0; e < NE; e++) {
        float v = lgv[e];
        #pragma unroll
        for (int mk = 1; mk < 64; mk <<= 1) v += __shfl_xor(v, mk);
        if (lane == e) impacc = v;
    }
    atomicAdd(&imp_s[lane], impacc);

    __syncthreads();
    if (tid < NE) {
        atomicAdd(&ws[tid], imp_s[tid]);
        atomicAdd(&ws[NE + tid], load_s[tid]);
    }
}

__global__ void finalize(const float* __restrict__ ws, float* __restrict__ out)
{
    const int l = threadIdx.x;   // one wave
    const float imp = ws[l];
    const float ld  = ws[NE + l];
    float is = imp, ls = ld;
    #pragma unroll
    for (int mk = 1; mk < 64; mk <<= 1) { is += __shfl_xor(is, mk); ls += __shfl_xor(ls, mk); }
    float v = (imp / fmaxf(is, 1e-9f)) * (ld / fmaxf(ls, 1e-9f));
    #pragma unroll
    for (int mk = 1; mk < 64; mk <<= 1) v += __shfl_xor(v, mk);
    if (l == 0) {
        out[4 * NT]     = (ws[128] / (float)NT) * 0.001f;        // router_z_loss
        out[4 * NT + 1] = v * (float)(NE * NE) * 0.01f;          // load_balance_loss
        out[4 * NT + 2] = ws[129] / (float)((size_t)NT * NE);    // logits_mean
    }
}

extern "C" void kernel_launch(void* const* d_in, const int* in_sizes, int n_in,
                              void* d_out, int out_size, void* d_ws, size_t ws_size,
                              hipStream_t stream) {
    const float* x = (const float*)d_in[0];
    const float* W = (const float*)d_in[1];
    float* out = (float*)d_out;
    float* ws  = (float*)d_ws;

    // pick k-split by available workspace (deterministic per environment)
    int kq_bits = 2;   // 4 slabs, 8.4 MB
    if (ws_size < (SLAB_OFF + 4ull * NT * NE) * 4) kq_bits = 1;
    if (ws_size < (SLAB_OFF + 2ull * NT * NE) * 4) kq_bits = 0;
    const int kq = 1 << kq_bits;
    const int nchunk = (ND >> kq_bits) / BK;

    hipMemsetAsync(ws, 0, 130 * sizeof(float), stream);
    hipLaunchKernelGGL(pass1, dim3(256 * kq), dim3(256), 0, stream,
                       x, W, ws, kq_bits, nchunk);
    hipLaunchKernelGGL(pass2, dim3(NT / 256), dim3(256), 0, stream, ws, out, kq);
    hipLaunchKernelGGL(finalize, dim3(1), dim3(64), 0, stream, ws, out);
}

// Round 5
// 99.188 us; speedup vs baseline: 5.5058x; 5.5058x over previous
//
#include <hip/hip_runtime.h>
#include <math.h>

// ---------------------------------------------------------------------------
// Fused MoE top-2 router, MI355X (gfx950) — round 5.
// R4 failed on VGPR spill: launch_bounds(256,4) capped regs at 128 but the
// T8xE8 tile needs ~175 live -> acc went to scratch (FETCH 632MB, WRITE 1.1GB,
// VALU 7%). R5: launch_bounds(256,2) (256-reg cap, no spill), split-K x2
// (512 blocks = 2 waves/SIMD resident), and x software-pipelined into
// registers half-a-chunk ahead (load->use ~512 cy) so 2-wave TLP + ILP covers
// L3/HBM latency. W double-buffered in LDS via global_load_lds (1 chunk ahead).
// Deterministic slab partials + pass2 epilogue (validated in R4).
// ---------------------------------------------------------------------------

#define NT 8192
#define ND 4096
#define NE 64
#define TB 32
#define BK 64             // k floats per chunk
#define SLAB_OFF 512      // ws[0..129] scalars; slabs after

__device__ __forceinline__ void gload16(const float* g, float* l) {
    __builtin_amdgcn_global_load_lds(
        (const __attribute__((address_space(1))) void*)g,
        (__attribute__((address_space(3))) void*)l, 16, 0, 0);
}

#define STAGE_W(buf, koff)                                                   \
    {                                                                        \
        _Pragma("unroll")                                                    \
        for (int r = 0; r < 4; r++) {                                        \
            int s = r * 256 + tid;                                           \
            gload16(W + (size_t)(s >> 4) * ND + (koff) + (s & 15) * 4,       \
                    &wbuf[buf][s << 2]);                                     \
        }                                                                    \
    }

#define LOADX(dst, off)                                                      \
    {                                                                        \
        _Pragma("unroll")                                                    \
        for (int t = 0; t < 8; t++)                                          \
            dst[t] = *reinterpret_cast<const float4*>(                       \
                xp + (size_t)t * ND + (off));                                \
    }

#define COMP(xv, buf, hoff)                                                  \
    {                                                                        \
        float4 wv[8];                                                        \
        _Pragma("unroll")                                                    \
        for (int e = 0; e < 8; e++)                                          \
            wv[e] = *reinterpret_cast<const float4*>(                        \
                &wbuf[buf][(eg * 8 + e) * BK + (hoff) + ks * 4]);            \
        _Pragma("unroll")                                                    \
        for (int e = 0; e < 8; e++) {                                        \
            _Pragma("unroll")                                                \
            for (int t = 0; t < 8; t++) {                                    \
                float a = acc[t][e];                                         \
                a = fmaf(xv[t].x, wv[e].x, a);                               \
                a = fmaf(xv[t].y, wv[e].y, a);                               \
                a = fmaf(xv[t].z, wv[e].z, a);                               \
                a = fmaf(xv[t].w, wv[e].w, a);                               \
                acc[t][e] = a;                                               \
            }                                                                \
        }                                                                    \
    }

__global__ __launch_bounds__(256, 2)
void pass1(const float* __restrict__ x, const float* __restrict__ W,
           float* __restrict__ ws, int kq_bits, int nchunk)
{
    __shared__ float wbuf[2][NE * BK];   // 2 x 16 KiB

    const int tid  = threadIdx.x;
    const int wave = tid >> 6;
    const int lane = tid & 63;
    const int eg   = lane >> 3;          // expert octet 0..7
    const int ks   = lane & 7;           // k slice 0..7 (x 4 floats)

    const int bq   = blockIdx.x >> 8;    // k-section index
    const int tb   = blockIdx.x & 255;
    const int tok0 = tb * TB + wave * 8;
    const int k0   = bq * (ND >> kq_bits);

    float acc[8][8];
    #pragma unroll
    for (int t = 0; t < 8; t++)
        #pragma unroll
        for (int e = 0; e < 8; e++) acc[t][e] = 0.f;

    const float* xp = x + (size_t)tok0 * ND + k0 + ks * 4;

    STAGE_W(0, k0);
    float4 xa[8], xb[8];
    LOADX(xa, 0);                        // first half of chunk 0
    __syncthreads();                     // wbuf[0] ready

    #pragma unroll 1
    for (int c = 0; c < nchunk; ++c) {
        const int b = c & 1;
        if (c + 1 < nchunk) STAGE_W(b ^ 1, k0 + (c + 1) * BK);
        LOADX(xb, c * BK + 32);          // second half (used ~512 cy later)
        COMP(xa, b, 0);
        if (c + 1 < nchunk) LOADX(xa, (c + 1) * BK);   // next chunk 1st half
        COMP(xb, b, 32);
        __syncthreads();                 // wbuf[b^1] ready / wbuf[b] reusable
    }

    // reduce over ks (lane bits 0..2)
    #pragma unroll
    for (int t = 0; t < 8; t++)
        #pragma unroll
        for (int e = 0; e < 8; e++) {
            float v = acc[t][e];
            v += __shfl_xor(v, 1);
            v += __shfl_xor(v, 2);
            v += __shfl_xor(v, 4);
            acc[t][e] = v;
        }

    // lane with ks==t writes token t's 8 experts
    float* slab = ws + SLAB_OFF + ((size_t)bq * NT + tok0) * NE;
    #pragma unroll
    for (int t = 0; t < 8; t++) {
        if (ks == t) {
            *reinterpret_cast<float4*>(slab + (size_t)t * NE + eg * 8) =
                make_float4(acc[t][0], acc[t][1], acc[t][2], acc[t][3]);
            *reinterpret_cast<float4*>(slab + (size_t)t * NE + eg * 8 + 4) =
                make_float4(acc[t][4], acc[t][5], acc[t][6], acc[t][7]);
        }
    }
}

__global__ __launch_bounds__(256)
void pass2(float* __restrict__ ws, float* __restrict__ out, int kq)
{
    __shared__ float imp_s[NE];
    __shared__ float load_s[NE];
    const int tid  = threadIdx.x;
    const int lane = tid & 63;
    if (tid < NE) { imp_s[tid] = 0.f; load_s[tid] = 0.f; }
    __syncthreads();

    const int tok = blockIdx.x * 256 + tid;
    float lgv[NE];
    {
        const float* p0 = ws + SLAB_OFF + (size_t)tok * NE;
        #pragma unroll
        for (int e4 = 0; e4 < 16; e4++) {
            float4 v = *reinterpret_cast<const float4*>(p0 + e4 * 4);
            lgv[e4*4+0] = v.x; lgv[e4*4+1] = v.y;
            lgv[e4*4+2] = v.z; lgv[e4*4+3] = v.w;
        }
        for (int q = 1; q < kq; q++) {
            const float* pq = ws + SLAB_OFF + ((size_t)q * NT + tok) * NE;
            #pragma unroll
            for (int e4 = 0; e4 < 16; e4++) {
                float4 v = *reinterpret_cast<const float4*>(pq + e4 * 4);
                lgv[e4*4+0] += v.x; lgv[e4*4+1] += v.y;
                lgv[e4*4+2] += v.z; lgv[e4*4+3] += v.w;
            }
        }
    }

    float m = -3.0e38f;
    #pragma unroll
    for (int e = 0; e < NE; e++) m = fmaxf(m, lgv[e]);
    float se = 0.f, ssum = 0.f;
    #pragma unroll
    for (int e = 0; e < NE; e++) { ssum += lgv[e]; se += __expf(lgv[e] - m); }
    const float lse = m + __logf(se);
    const float inv = 1.f / se;

    #pragma unroll
    for (int e = 0; e < NE; e++) lgv[e] = __expf(lgv[e] - m) * inv;

    float v1 = -3.0e38f, v2 = -3.0e38f;
    int   i1 = 0, i2 = 0;
    #pragma unroll
    for (int e = 0; e < NE; e++) {
        const float v = lgv[e];
        if (v > v1)      { v2 = v1; i2 = i1; v1 = v; i1 = e; }
        else if (v > v2) { v2 = v;  i2 = e; }
    }
    const float dn = fmaxf(v1 + v2, 1e-9f);

    out[2 * tok]              = (float)i1;
    out[2 * tok + 1]          = (float)i2;
    out[2 * NT + 2 * tok]     = v1 / dn;
    out[2 * NT + 2 * tok + 1] = v2 / dn;
    atomicAdd(&load_s[i1], 1.0f);

    float zv = lse * lse, sv = ssum;
    #pragma unroll
    for (int mk = 1; mk < 64; mk <<= 1) {
        zv += __shfl_xor(zv, mk);
        sv += __shfl_xor(sv, mk);
    }
    if (lane == 0) { atomicAdd(&ws[128], zv); atomicAdd(&ws[129], sv); }

    float impacc = 0.f;
    #pragma unroll
    for (int e = 0; e < NE; e++) {
        float v = lgv[e];
        #pragma unroll
        for (int mk = 1; mk < 64; mk <<= 1) v += __shfl_xor(v, mk);
        if (lane == e) impacc = v;
    }
    atomicAdd(&imp_s[lane], impacc);

    __syncthreads();
    if (tid < NE) {
        atomicAdd(&ws[tid], imp_s[tid]);
        atomicAdd(&ws[NE + tid], load_s[tid]);
    }
}

__global__ void finalize(const float* __restrict__ ws, float* __restrict__ out)
{
    const int l = threadIdx.x;   // one wave
    const float imp = ws[l];
    const float ld  = ws[NE + l];
    float is = imp, ls = ld;
    #pragma unroll
    for (int mk = 1; mk < 64; mk <<= 1) { is += __shfl_xor(is, mk); ls += __shfl_xor(ls, mk); }
    float v = (imp / fmaxf(is, 1e-9f)) * (ld / fmaxf(ls, 1e-9f));
    #pragma unroll
    for (int mk = 1; mk < 64; mk <<= 1) v += __shfl_xor(v, mk);
    if (l == 0) {
        out[4 * NT]     = (ws[128] / (float)NT) * 0.001f;        // router_z_loss
        out[4 * NT + 1] = v * (float)(NE * NE) * 0.01f;          // load_balance_loss
        out[4 * NT + 2] = ws[129] / (float)((size_t)NT * NE);    // logits_mean
    }
}

extern "C" void kernel_launch(void* const* d_in, const int* in_sizes, int n_in,
                              void* d_out, int out_size, void* d_ws, size_t ws_size,
                              hipStream_t stream) {
    const float* x = (const float*)d_in[0];
    const float* W = (const float*)d_in[1];
    float* out = (float*)d_out;
    float* ws  = (float*)d_ws;

    int kq_bits = 1;   // split-K x2: 512 blocks = 2 blocks/CU
    if (ws_size < (SLAB_OFF + 2ull * NT * NE) * 4) kq_bits = 0;
    const int kq = 1 << kq_bits;
    const int nchunk = (ND >> kq_bits) / BK;

    hipMemsetAsync(ws, 0, 130 * sizeof(float), stream);
    hipLaunchKernelGGL(pass1, dim3(256 * kq), dim3(256), 0, stream,
                       x, W, ws, kq_bits, nchunk);
    hipLaunchKernelGGL(pass2, dim3(NT / 256), dim3(256), 0, stream, ws, out, kq);
    hipLaunchKernelGGL(finalize, dim3(1), dim3(64), 0, stream, ws, out);
}